// Round 7
// baseline (16690.204 us; speedup 1.0000x reference)
//
#include <hip/hip_runtime.h>

typedef unsigned short u16;
typedef unsigned long long u64;
typedef __bf16 bf16_t;
typedef bf16_t bf16x8 __attribute__((ext_vector_type(8)));
typedef float f32x4 __attribute__((ext_vector_type(4)));

#define DEVFN static __device__ __forceinline__

constexpr int S_ = 512, B_ = 32, H_ = 512, E_ = 1024;
constexpr int SB_ = S_ * B_;                 // 16384

// ---------------- d_out offsets (floats) ----------------
constexpr size_t OUT_FH  = 0;                 // final_h (4,32,512)
constexpr size_t OUT_FC  = 65536;             // final_c (4,32,512)
constexpr size_t OUT_X   = 131072;            // x (512,32,1024)
constexpr size_t OUT_PEN = 16908288;          // penalty (scalar)
constexpr size_t OUT_PE  = 16908289;          // pred_emb (512,32,1024)

// ---------------- ws offsets (bytes) ----------------
constexpr size_t WS_SLOTS = 0;                          // [4][64][4] u32 = 4096
constexpr size_t WS_STAG  = 4096;                       // [2][64][4] u32 = 2048
constexpr size_t WS_PEN   = 6144;                       // 256
constexpr size_t WS_SPART = 6400;                       // [2][3][32][32] f32 = 24576
constexpr size_t WS_HG    = 30976;                      // [2][2][32][512] bf16 = 131072 (shared scan0/scan1)
constexpr size_t WS_WET   = 237824;                     // 512x1024 bf16
constexpr size_t WS_WCT   = 1286400;                    // 512x512 bf16
constexpr size_t WS_WIH0  = 1810688;                    // [2][2048][1024] bf16
constexpr size_t WS_WHH0  = 10199296;                   // [2][2048][512] bf16
constexpr size_t WS_WIH1  = 14393600;
constexpr size_t WS_WHH1  = 22782208;
constexpr size_t WS_WG    = 26976512;                   // [1024][2048] bf16
constexpr size_t WS_EK    = 31170816;                   // [3][SB][1024] bf16
constexpr size_t WS_ET    = 131834112;                  // [3][SB][512] f32
constexpr size_t WS_PREDF = 232497408;                  // [SB][1024] bf16
constexpr size_t WS_PREDB = 266051840;
constexpr size_t WS_OUT0F = 299606272;                  // [SB][512] bf16
constexpr size_t WS_OUT0B = 316383488;                  // end ~318MB (same as R6)

// ---------------- helpers ----------------
DEVFN u16 f2bf(float f) {
  union { float f; unsigned u; } v; v.f = f;
  unsigned u = v.u;
  unsigned r = (u + 0x7fffu + ((u >> 16) & 1u)) >> 16;
  return (u16)r;
}
DEVFN float bf2f(u16 h) {
  union { unsigned u; float f; } v; v.u = ((unsigned)h) << 16;
  return v.f;
}
DEVFN float sigm(float x) { return 1.f / (1.f + __expf(-x)); }
DEVFN float tanh_f(float x) { float e = __expf(2.f * x); return 1.f - 2.f / (e + 1.f); }
DEVFN bf16x8 ld_bf8(const u16* p) { return *reinterpret_cast<const bf16x8*>(p); }
DEVFN f32x4 mfma_bf(bf16x8 a, bf16x8 b, f32x4 c) {
  return __builtin_amdgcn_mfma_f32_16x16x32_bf16(a, b, c, 0, 0, 0);
}
// XOR-swizzled LDS tile access (weights / GEMM staging)
DEVFN void lds_st16(u16* base, int row, int rowBytes, int byteCol, bf16x8 v) {
  *reinterpret_cast<bf16x8*>((char*)base + row * rowBytes + (byteCol ^ ((row & 7) << 4))) = v;
}
DEVFN bf16x8 lds_ld16(const u16* base, int row, int rowBytes, int byteCol) {
  return *reinterpret_cast<const bf16x8*>((const char*)base + row * rowBytes + (byteCol ^ ((row & 7) << 4)));
}

// Coherent-point (sc1) accessors — protocol proven in rounds 5/6.
DEVFN u64 coh_ld64(const u64* p) {
  return __hip_atomic_load(p, __ATOMIC_RELAXED, __HIP_MEMORY_SCOPE_AGENT);
}
DEVFN void coh_st64(u64* p, u64 v) {
  __hip_atomic_store(p, v, __ATOMIC_RELAXED, __HIP_MEMORY_SCOPE_AGENT);
}
DEVFN unsigned coh_ld32(const unsigned* p) {
  return __hip_atomic_load(p, __ATOMIC_RELAXED, __HIP_MEMORY_SCOPE_AGENT);
}
DEVFN void coh_st32(unsigned* p, unsigned v) {
  __hip_atomic_store(p, v, __ATOMIC_RELAXED, __HIP_MEMORY_SCOPE_AGENT);
}
DEVFN void wave_vmcnt0() { asm volatile("s_waitcnt vmcnt(0)" ::: "memory"); }

// 64-slot poll (wave-level): lane i polls slot i; compiler barrier on exit so
// dependent data loads are not hoisted above the poll.
DEVFN void poll64(const unsigned* tags, unsigned target) {
  int lane = threadIdx.x & 63;
  for (;;) {
    unsigned v = coh_ld32(tags + lane * 4);
    if (__all(v >= target)) break;
    __builtin_amdgcn_s_sleep(1);
  }
  asm volatile("" ::: "memory");
}

// ---------------- fp32 -> bf16 convert ----------------
__global__ void k_f2bf(const float* __restrict__ src, u16* __restrict__ dst, int n) {
  for (int i = blockIdx.x * blockDim.x + threadIdx.x; i < n; i += gridDim.x * blockDim.x)
    dst[i] = f2bf(src[i]);
}

// ---------------- gather embeddings + penalty ----------------
__global__ __launch_bounds__(256) void k_gather(
    const int* __restrict__ seq, const int* __restrict__ lengths,
    const float* __restrict__ emb1, const float* __restrict__ emb2, const float* __restrict__ emb3,
    u16* __restrict__ eK, float* __restrict__ pen) {
  int s = blockIdx.x;              // = t*32 + b
  int t = s >> 5, b = s & 31;
  int tid = threadIdx.x;
  int tok = seq[s];
  const float4* p1 = (const float4*)(emb1 + (size_t)tok * 1024);
  const float4* p2 = (const float4*)(emb2 + (size_t)tok * 1024);
  const float4* p3 = (const float4*)(emb3 + (size_t)tok * 1024);
  float4 a = p1[tid], c = p2[tid], d = p3[tid];
  size_t rb = (size_t)s * 1024 + tid * 4;
  uint2 pk;
  pk.x = f2bf(a.x) | ((unsigned)f2bf(a.y) << 16); pk.y = f2bf(a.z) | ((unsigned)f2bf(a.w) << 16);
  *(uint2*)(eK + rb) = pk;
  pk.x = f2bf(c.x) | ((unsigned)f2bf(c.y) << 16); pk.y = f2bf(c.z) | ((unsigned)f2bf(c.w) << 16);
  *(uint2*)(eK + (size_t)SB_ * 1024 + rb) = pk;
  pk.x = f2bf(d.x) | ((unsigned)f2bf(d.y) << 16); pk.y = f2bf(d.z) | ((unsigned)f2bf(d.w) << 16);
  *(uint2*)(eK + (size_t)2 * SB_ * 1024 + rb) = pk;
  float v[6];
  v[0] = a.x*c.x + a.y*c.y + a.z*c.z + a.w*c.w;
  v[1] = a.x*d.x + a.y*d.y + a.z*d.z + a.w*d.w;
  v[2] = c.x*d.x + c.y*d.y + c.z*d.z + c.w*d.w;
  v[3] = a.x*a.x + a.y*a.y + a.z*a.z + a.w*a.w;
  v[4] = c.x*c.x + c.y*c.y + c.z*c.z + c.w*c.w;
  v[5] = d.x*d.x + d.y*d.y + d.z*d.z + d.w*d.w;
  for (int i = 0; i < 6; ++i)
    for (int m = 1; m < 64; m <<= 1) v[i] += __shfl_xor(v[i], m);
  __shared__ float red[4][6];
  int wid = tid >> 6, lane = tid & 63;
  if (lane == 0) for (int i = 0; i < 6; ++i) red[wid][i] = v[i];
  __syncthreads();
  if (tid == 0) {
    float r[6];
    for (int i = 0; i < 6; ++i) r[i] = red[0][i] + red[1][i] + red[2][i] + red[3][i];
    float c12 = r[0] / fmaxf(sqrtf(r[3]) * sqrtf(r[4]), 1e-8f);
    float c13 = r[1] / fmaxf(sqrtf(r[3]) * sqrtf(r[5]), 1e-8f);
    float c23 = r[2] / fmaxf(sqrtf(r[4]) * sqrtf(r[5]), 1e-8f);
    float p = fmaxf(c12 - 0.3f, 0.f) + fmaxf(c13 - 0.3f, 0.f) + fmaxf(c23 - 0.3f, 0.f);
    if (t < lengths[b] && p > 0.f) atomicAdd(pen, 2.f * p);   // fwd + bwd identical sums
  }
}

// ---------------- GEMM: ET = EK @ W_et^T + b_et ----------------
__global__ __launch_bounds__(256) void k_gemm_et(
    const u16* __restrict__ A, const u16* __restrict__ Bw,
    const float* __restrict__ bias, float* __restrict__ C) {
  int bm = blockIdx.x % 384, bn = blockIdx.x / 384;
  int m0 = bm * 128, n0 = bn * 128;
  __shared__ u16 sA[128 * 64], sB[128 * 64];
  int tid = threadIdx.x, wid = tid >> 6, lane = tid & 63;
  int wm = wid & 1, wn = wid >> 1;
  f32x4 acc[4][4] = {};
  for (int kb = 0; kb < 16; ++kb) {
    __syncthreads();
    for (int c = tid; c < 1024; c += 256) {
      int row = c >> 3, q = c & 7;
      lds_st16(sA, row, 128, q * 16, ld_bf8(A + (size_t)(m0 + row) * 1024 + kb * 64 + q * 8));
      lds_st16(sB, row, 128, q * 16, ld_bf8(Bw + (size_t)(n0 + row) * 1024 + kb * 64 + q * 8));
    }
    __syncthreads();
    for (int kk = 0; kk < 2; ++kk) {
      bf16x8 af[4], bf[4];
      int bc = kk * 64 + (lane >> 4) * 16;
      for (int i = 0; i < 4; ++i) {
        af[i] = lds_ld16(sA, wm * 64 + i * 16 + (lane & 15), 128, bc);
        bf[i] = lds_ld16(sB, wn * 64 + i * 16 + (lane & 15), 128, bc);
      }
      for (int i = 0; i < 4; ++i)
        for (int j = 0; j < 4; ++j) acc[i][j] = mfma_bf(af[i], bf[j], acc[i][j]);
    }
  }
  for (int i = 0; i < 4; ++i)
    for (int j = 0; j < 4; ++j) {
      int m = m0 + wm * 64 + i * 16 + (lane >> 4) * 4;
      int n = n0 + wn * 64 + j * 16 + (lane & 15);
      float bn_ = bias[n & 511];
      for (int r = 0; r < 4; ++r) C[(size_t)(m + r) * 512 + n] = acc[i][j][r] + bn_;
    }
}

// ---------------- GEMM: gate + pred_emb epilogue ----------------
__global__ __launch_bounds__(256) void k_gemm_gate(
    const u16* __restrict__ pF, const u16* __restrict__ pB, const u16* __restrict__ Wg,
    const float* __restrict__ bias, float* __restrict__ outPE) {
  int bm = blockIdx.x % 128, bn = blockIdx.x / 128;
  int m0 = bm * 128, n0 = bn * 128;
  __shared__ u16 sA[128 * 64], sB[128 * 64];
  int tid = threadIdx.x, wid = tid >> 6, lane = tid & 63;
  int wm = wid & 1, wn = wid >> 1;
  f32x4 acc[4][4] = {};
  for (int kb = 0; kb < 32; ++kb) {
    __syncthreads();
    const u16* Asrc = (kb < 16) ? pF : pB;
    int kof = (kb < 16) ? kb * 64 : (kb - 16) * 64;
    for (int c = tid; c < 1024; c += 256) {
      int row = c >> 3, q = c & 7;
      lds_st16(sA, row, 128, q * 16, ld_bf8(Asrc + (size_t)(m0 + row) * 1024 + kof + q * 8));
      lds_st16(sB, row, 128, q * 16, ld_bf8(Wg + (size_t)(n0 + row) * 2048 + kb * 64 + q * 8));
    }
    __syncthreads();
    for (int kk = 0; kk < 2; ++kk) {
      bf16x8 af[4], bf[4];
      int bc = kk * 64 + (lane >> 4) * 16;
      for (int i = 0; i < 4; ++i) {
        af[i] = lds_ld16(sA, wm * 64 + i * 16 + (lane & 15), 128, bc);
        bf[i] = lds_ld16(sB, wn * 64 + i * 16 + (lane & 15), 128, bc);
      }
      for (int i = 0; i < 4; ++i)
        for (int j = 0; j < 4; ++j) acc[i][j] = mfma_bf(af[i], bf[j], acc[i][j]);
    }
  }
  for (int i = 0; i < 4; ++i)
    for (int j = 0; j < 4; ++j) {
      int m = m0 + wm * 64 + i * 16 + (lane >> 4) * 4;
      int n = n0 + wn * 64 + j * 16 + (lane & 15);
      float bn_ = bias[n];
      for (int r = 0; r < 4; ++r) {
        float g = sigm(acc[i][j][r] + bn_);
        size_t idx = (size_t)(m + r) * 1024 + n;
        float a = bf2f(pF[idx]), b = bf2f(pB[idx]);
        outPE[idx] = a * g + b * (1.f - g);
      }
    }
}

// ---------------- layer-0 bidirectional scan ----------------
__global__ __launch_bounds__(256, 1) void k_scan0(
    const u16* __restrict__ eK, const float* __restrict__ eT,
    const u16* __restrict__ wIh0, const u16* __restrict__ wHh0, const u16* __restrict__ wCt,
    const float* __restrict__ Wsc, const float* __restrict__ bct,
    const float* __restrict__ bih, const float* __restrict__ bhh,
    const int* __restrict__ lengths,
    const float* __restrict__ h0f, const float* __restrict__ c0f,
    const float* __restrict__ h0b, const float* __restrict__ c0b,
    u16* __restrict__ hg, float* __restrict__ spart,
    u16* __restrict__ out0F, u16* __restrict__ out0B,
    u16* __restrict__ predF, u16* __restrict__ predB,
    float* __restrict__ dout, unsigned* __restrict__ slots, unsigned* __restrict__ stag) {
  const int dir = blockIdx.x >> 6;
  const int r   = blockIdx.x & 63;
  const int tid = threadIdx.x, wid = tid >> 6, lane = tid & 63;

  const u16* Wih = wIh0 + (size_t)dir * 2048 * 1024;
  const u16* Whh = wHh0 + (size_t)dir * 2048 * 512;
  const float* bi = bih + dir * 2048;
  const float* bh = bhh + dir * 2048;
  u16* out0 = dir ? out0B : out0F;
  u16* predD = dir ? predB : predF;
  const float* h0 = dir ? h0b : h0f;
  const float* c0 = dir ? c0b : c0f;
  u16* myhg = hg + (size_t)dir * 2 * 32 * 512;          // [buf][32][512]
  float* spartD = spart + (size_t)dir * 3 * 32 * 32;
  unsigned* slotg = slots + dir * 64 * 4;
  unsigned* stagD = stag + dir * 64 * 4;

  __shared__ u16 sWih[32 * 1024];      // 32 n-rows x 1024 k (swizzled)
  __shared__ u16 sWhh[32 * 512];
  __shared__ u16 sHpub[256];
  __shared__ float sPW[3][32][32];
  __shared__ float sHW[32][32];
  __shared__ float sSK[3][32];
  __shared__ float sWt[32][4];
  __shared__ float sBias[32];

  // ---- load weight slices into LDS (n = q*512 + r*8 + jl) ----
  for (int c = tid; c < 4096; c += 256) {
    int ln = c >> 7, q = c & 127;
    int n = (ln >> 3) * 512 + r * 8 + (ln & 7);
    lds_st16(sWih, ln, 2048, q * 16, ld_bf8(Wih + (size_t)n * 1024 + q * 8));
  }
  for (int c = tid; c < 2048; c += 256) {
    int ln = c >> 6, q = c & 63;
    int n = (ln >> 3) * 512 + r * 8 + (ln & 7);
    lds_st16(sWhh, ln, 1024, q * 16, ld_bf8(Whh + (size_t)n * 512 + q * 8));
  }
  if (tid < 32) {
    int n = (tid >> 3) * 512 + r * 8 + (tid & 7);
    sBias[tid] = bi[n] + bh[n];
  }

  const int pb = tid >> 3, pj = tid & 7;     // phase-2 ownership (b, j-local)
  const int gj = r * 8 + pj;
  float hreg = h0[gj], creg = c0[gj];
  const int lenb = lengths[pb];
  const int Lmax = lengths[0];               // sorted descending

  const int Mt = wid & 1, Nt = wid >> 1;
  const int arow = Mt * 16 + (lane & 15);    // b-row for A fragments
  const int lenrow = lengths[arow];
  const int kq = lane >> 4;
  const int colN = Nt * 16 + (lane & 15);
  const bool isctx = (r < 32) && (wid < 2);
  int lctx[4];
  if (isctx)
    for (int reg = 0; reg < 4; ++reg) lctx[reg] = lengths[Mt * 16 + kq * 4 + reg];

  // ---- initial h publish into buf0 + initial barrier ----
  sHpub[tid] = f2bf(hreg);
  __syncthreads();
  if (wid == 0) {
    u64 v = *reinterpret_cast<const u64*>(sHpub + lane * 4);
    coh_st64((u64*)myhg + (size_t)(lane >> 1) * 128 + r * 2 + (lane & 1), v);
    wave_vmcnt0();
    if (lane == 0) coh_st32(slotg + r * 4, 1u);
  }
  if (wid == 0) poll64(slotg, 1u);
  __syncthreads();

  // eT prefetch (step 0)
  float petU[3][4];
  if (isctx) {
    int j = r * 16 + (lane & 15);
    for (int reg = 0; reg < 4; ++reg) {
      int b = Mt * 16 + kq * 4 + reg;
      int lb = lctx[reg];
      int pos = (dir == 0) ? 0 : (lb - 1);
      size_t rowoff = (size_t)(pos * 32 + b) * 512 + j;
      for (int k = 0; k < 3; ++k) petU[k][reg] = eT[(size_t)k * SB_ * 512 + rowoff];
    }
  }

  for (int t = 0; t < Lmax; ++t) {
    const bool last = (t == Lmax - 1);
    // ===== (A) h fragments direct from coherent buffer (no LDS) =====
    bf16x8 hf[16];
    {
      const u64* hrow = (const u64*)(myhg + (size_t)(t & 1) * 32 * 512) +
                        (size_t)arow * 128 + kq * 2;
      u64 lo[16], hi[16];
#pragma unroll
      for (int kb = 0; kb < 16; ++kb) {
        lo[kb] = coh_ld64(hrow + kb * 8);
        hi[kb] = coh_ld64(hrow + kb * 8 + 1);
      }
#pragma unroll
      for (int kb = 0; kb < 16; ++kb) {
        union { u64 q[2]; bf16x8 v; } u; u.q[0] = lo[kb]; u.q[1] = hi[kb];
        hf[kb] = u.v;
      }
    }
    // ===== (B) hWhh (all waves) =====
    {
      f32x4 acc = {0.f, 0.f, 0.f, 0.f};
#pragma unroll
      for (int kb = 0; kb < 16; ++kb)
        acc = mfma_bf(hf[kb], lds_ld16(sWhh, colN, 1024, (kb * 32 + kq * 8) * 2), acc);
      int rb = Mt * 16 + kq * 4;
      for (int reg = 0; reg < 4; ++reg) sHW[rb + reg][colN] = acc[reg];
    }
    // ctx + score partials + tagged publish (producer waves)
    if (isctx) {
      f32x4 acc = {0.f, 0.f, 0.f, 0.f};
      int j = r * 16 + (lane & 15);
      const u16* Wctp = wCt + (size_t)j * 512;
#pragma unroll
      for (int kb = 0; kb < 16; ++kb)
        acc = mfma_bf(hf[kb], ld_bf8(Wctp + kb * 32 + kq * 8), acc);
      float wsc = Wsc[j], bctj = bct[j];
      for (int k = 0; k < 3; ++k)
        for (int reg = 0; reg < 4; ++reg) {
          float v = tanh_f(petU[k][reg] + acc[reg] + bctj) * wsc;
          v += __shfl_xor(v, 1); v += __shfl_xor(v, 2);
          v += __shfl_xor(v, 4); v += __shfl_xor(v, 8);
          if ((lane & 15) == 0) {
            int b = Mt * 16 + kq * 4 + reg;
            union { float f; unsigned u; } w; w.f = v;
            coh_st32((unsigned*)(spartD + (k * 32 + b) * 32 + r), w.u);
          }
        }
      wave_vmcnt0();
      if (lane == 0) coh_st32(stagD + (r * 2 + Mt) * 4, (unsigned)(t + 1));
    }
    // eT prefetch for t+1 (issued early; drain hidden under PW + polls)
    float petN[3][4];
    if (isctx && t + 1 < Lmax) {
      int j = r * 16 + (lane & 15);
      for (int reg = 0; reg < 4; ++reg) {
        int b = Mt * 16 + kq * 4 + reg;
        int lb = lctx[reg];
        int tn = t + 1;
        int pos = (dir == 0) ? tn : ((tn < lb) ? (lb - 1 - tn) : tn);
        size_t rowoff = (size_t)(pos * 32 + b) * 512 + j;
        for (int k = 0; k < 3; ++k) petN[k][reg] = eT[(size_t)k * SB_ * 512 + rowoff];
      }
    }
    // ===== (C) PW GEMM (shadow work, all waves) =====
    {
      int posA = (dir == 0) ? t : ((t < lenrow) ? (lenrow - 1 - t) : t);
      size_t ebase = (size_t)(posA * 32 + arow) * 1024;
      for (int k = 0; k < 3; ++k) {
        const u16* Ek = eK + (size_t)k * SB_ * 1024 + ebase;
        f32x4 acc = {0.f, 0.f, 0.f, 0.f};
#pragma unroll 4
        for (int kb = 0; kb < 32; ++kb)
          acc = mfma_bf(ld_bf8(Ek + kb * 32 + kq * 8),
                        lds_ld16(sWih, colN, 2048, (kb * 32 + kq * 8) * 2), acc);
        int rb = Mt * 16 + kq * 4;
        for (int reg = 0; reg < 4; ++reg) sPW[k][rb + reg][colN] = acc[reg];
      }
    }
    // ===== (D) consume score partials (waves 0-1 poll producer tags) =====
    if (wid < 2) poll64(stagD, (unsigned)(t + 1));
    if (tid < 96) {
      int k = tid >> 5, b = tid & 31;
      const u64* sp = (const u64*)(spartD + (k * 32 + b) * 32);
      float s = 0.f;
#pragma unroll
      for (int i = 0; i < 16; ++i) {
        union { u64 u; float f[2]; } w; w.u = coh_ld64(sp + i);
        s += w.f[0] + w.f[1];
      }
      sSK[k][b] = s;
    }
    __syncthreads();
    if (tid < 32) {
      float s0 = sSK[0][tid], s1 = sSK[1][tid], s2 = sSK[2][tid];
      float mx = fmaxf(s0, fmaxf(s1, s2));
      float e0 = __expf(s0 - mx), e1 = __expf(s1 - mx), e2 = __expf(s2 - mx);
      float inv = 1.f / (e0 + e1 + e2);
      sWt[tid][0] = e0 * inv; sWt[tid][1] = e1 * inv; sWt[tid][2] = e2 * inv;
    }
    __syncthreads();
    // ===== (F) gate + cell update =====
    float w0 = sWt[pb][0], w1 = sWt[pb][1], w2 = sWt[pb][2];
    float h2, c2; bool m; int pos;
    {
      float gq[4];
      for (int q = 0; q < 4; ++q) {
        int cl = q * 8 + pj;
        gq[q] = w0 * sPW[0][pb][cl] + w1 * sPW[1][pb][cl] + w2 * sPW[2][pb][cl]
              + sHW[pb][cl] + sBias[cl];
      }
      float ig = sigm(gq[0]), fg = sigm(gq[1]), gg = tanh_f(gq[2]), og = sigm(gq[3]);
      c2 = fg * creg + ig * gg;
      h2 = og * tanh_f(c2);
      m = (t < lenb);
      if (m) { creg = c2; hreg = h2; }
      pos = (dir == 0) ? t : ((t < lenb) ? (lenb - 1 - t) : t);
      sHpub[tid] = f2bf(hreg);
    }
    __syncthreads();   // sHpub ready for wave 0
    // ===== (H) h publish + arrive (wave 0 only) =====
    if (!last && wid == 0) {
      u64 v = *reinterpret_cast<const u64*>(sHpub + lane * 4);
      coh_st64((u64*)(myhg + (size_t)((t + 1) & 1) * 32 * 512) +
               (size_t)(lane >> 1) * 128 + r * 2 + (lane & 1), v);
      wave_vmcnt0();
      if (lane == 0) coh_st32(slotg + r * 4, (unsigned)(t + 2));
    }
    // ===== (I) B-shadow: out0 + preds (plain stores; kernel-boundary coherence) =====
    {
      out0[(size_t)(pos * 32 + pb) * 512 + gj] = f2bf(m ? h2 : 0.f);
      size_t rowb = (size_t)(pos * 32 + pb) * 1024;
      int e0i = r * 16 + (tid & 7) * 2;
      for (int ii = 0; ii < 2; ++ii) {
        int e = e0i + ii;
        float xv = w0 * bf2f(eK[rowb + e])
                 + w1 * bf2f(eK[(size_t)SB_ * 1024 + rowb + e])
                 + w2 * bf2f(eK[(size_t)2 * SB_ * 1024 + rowb + e]);
        predD[rowb + e] = f2bf(m ? xv : 0.f);
      }
    }
    // rotate eT prefetch
    if (isctx)
      for (int k = 0; k < 3; ++k)
        for (int reg = 0; reg < 4; ++reg) petU[k][reg] = petN[k][reg];
    // ===== (J) wait for all h publishes =====
    if (!last) {
      if (wid == 0) poll64(slotg, (unsigned)(t + 2));
      __syncthreads();
    }
  }

  // epilogue: finals + tail-zero rows [Lmax*32, SB)
  dout[OUT_FH + ((size_t)dir * 32 + pb) * 512 + gj] = hreg;
  dout[OUT_FC + ((size_t)dir * 32 + pb) * 512 + gj] = creg;
  for (int row = Lmax * 32 + r; row < SB_; row += 64) {
    if (tid < 128) ((u64*)(out0 + (size_t)row * 512))[tid] = 0;
    ((u64*)(predD + (size_t)row * 1024))[tid] = 0;
  }
}

// ---------------- layer-1 bidirectional scan ----------------
__global__ __launch_bounds__(256, 1) void k_scan1(
    const u16* __restrict__ out0F, const u16* __restrict__ out0B,
    const u16* __restrict__ wIh1, const u16* __restrict__ wHh1,
    const float* __restrict__ bih, const float* __restrict__ bhh,
    const int* __restrict__ lengths,
    const float* __restrict__ h0f, const float* __restrict__ c0f,
    const float* __restrict__ h0b, const float* __restrict__ c0b,
    u16* __restrict__ hg, float* __restrict__ dout, unsigned* __restrict__ slots) {
  const int dir = blockIdx.x >> 6;
  const int r   = blockIdx.x & 63;
  const int tid = threadIdx.x, wid = tid >> 6, lane = tid & 63;

  const u16* Wih = wIh1 + (size_t)dir * 2048 * 1024;
  const u16* Whh = wHh1 + (size_t)dir * 2048 * 512;
  const float* bi = bih + (2 + dir) * 2048;
  const float* bh = bhh + (2 + dir) * 2048;
  const float* h0 = dir ? h0b : h0f;
  const float* c0 = dir ? c0b : c0f;
  unsigned* slotg = slots + (2 + dir) * 64 * 4;

  __shared__ u16 sWih[32 * 1024];
  __shared__ u16 sWhh[32 * 512];
  __shared__ u16 sHpub[256];
  __shared__ float sG[32][32];
  __shared__ float sBias[32];

  for (int c = tid; c < 4096; c += 256) {
    int ln = c >> 7, q = c & 127;
    int n = (ln >> 3) * 512 + r * 8 + (ln & 7);
    lds_st16(sWih, ln, 2048, q * 16, ld_bf8(Wih + (size_t)n * 1024 + q * 8));
  }
  for (int c = tid; c < 2048; c += 256) {
    int ln = c >> 6, q = c & 63;
    int n = (ln >> 3) * 512 + r * 8 + (ln & 7);
    lds_st16(sWhh, ln, 1024, q * 16, ld_bf8(Whh + (size_t)n * 512 + q * 8));
  }
  if (tid < 32) {
    int n = (tid >> 3) * 512 + r * 8 + (tid & 7);
    sBias[tid] = bi[n] + bh[n];
  }

  const int pb = tid >> 3, pj = tid & 7;
  const int gj = r * 8 + pj;
  float hreg = h0[gj], creg = c0[gj];
  const int lenb = lengths[pb];
  const int Lmax = lengths[0];
  const int Mt = wid & 1, Nt = wid >> 1;
  const int arow = Mt * 16 + (lane & 15);
  const int lenrow = lengths[arow];
  const int kq = lane >> 4;
  const int colN = Nt * 16 + (lane & 15);

  __syncthreads();   // sWih staged
  // x@Wih for t=0
  f32x4 accx = {0.f, 0.f, 0.f, 0.f};
  {
    int posA = (dir == 0) ? 0 : (lenrow - 1);
    size_t rowb = (size_t)(posA * 32 + arow) * 512;
#pragma unroll 4
    for (int kb = 0; kb < 32; ++kb) {
      const u16* Asrc = (kb < 16) ? (out0F + rowb + kb * 32 + kq * 8)
                                  : (out0B + rowb + (kb - 16) * 32 + kq * 8);
      accx = mfma_bf(ld_bf8(Asrc), lds_ld16(sWih, colN, 2048, (kb * 32 + kq * 8) * 2), accx);
    }
  }

  // initial h publish into buf0 ([buf][dir][32][512]) + initial barrier
  sHpub[tid] = f2bf(hreg);
  __syncthreads();
  if (wid == 0) {
    u64 v = *reinterpret_cast<const u64*>(sHpub + lane * 4);
    coh_st64((u64*)(hg + (size_t)(0 * 2 + dir) * 32 * 512) +
             (size_t)(lane >> 1) * 128 + r * 2 + (lane & 1), v);
    wave_vmcnt0();
    if (lane == 0) coh_st32(slotg + r * 4, 1u);
  }
  if (wid == 0) poll64(slotg, 1u);
  __syncthreads();

  for (int t = 0; t < Lmax; ++t) {
    const bool last = (t == Lmax - 1);
    // (A) h fragments direct
    bf16x8 hf[16];
    {
      const u64* hrow = (const u64*)(hg + (size_t)((t & 1) * 2 + dir) * 32 * 512) +
                        (size_t)arow * 128 + kq * 2;
      u64 lo[16], hi[16];
#pragma unroll
      for (int kb = 0; kb < 16; ++kb) {
        lo[kb] = coh_ld64(hrow + kb * 8);
        hi[kb] = coh_ld64(hrow + kb * 8 + 1);
      }
#pragma unroll
      for (int kb = 0; kb < 16; ++kb) {
        union { u64 q[2]; bf16x8 v; } u; u.q[0] = lo[kb]; u.q[1] = hi[kb];
        hf[kb] = u.v;
      }
    }
    // (B) h@Whh on top of prefetched x@Wih
    f32x4 acc = accx;
#pragma unroll
    for (int kb = 0; kb < 16; ++kb)
      acc = mfma_bf(hf[kb], lds_ld16(sWhh, colN, 1024, (kb * 32 + kq * 8) * 2), acc);
    {
      int rb = Mt * 16 + kq * 4;
      for (int reg = 0; reg < 4; ++reg) sG[rb + reg][colN] = acc[reg];
    }
    __syncthreads();
    // (F) gate
    float h2, c2; bool m; int pos;
    {
      float gq[4];
      for (int q = 0; q < 4; ++q) gq[q] = sG[pb][q * 8 + pj] + sBias[q * 8 + pj];
      float ig = sigm(gq[0]), fg = sigm(gq[1]), gg = tanh_f(gq[2]), og = sigm(gq[3]);
      c2 = fg * creg + ig * gg;
      h2 = og * tanh_f(c2);
      m = (t < lenb);
      if (m) { creg = c2; hreg = h2; }
      pos = (dir == 0) ? t : ((t < lenb) ? (lenb - 1 - t) : t);
      sHpub[tid] = f2bf(hreg);
    }
    __syncthreads();
    // (H) publish + arrive (wave 0)
    if (!last && wid == 0) {
      u64 v = *reinterpret_cast<const u64*>(sHpub + lane * 4);
      coh_st64((u64*)(hg + (size_t)(((t + 1) & 1) * 2 + dir) * 32 * 512) +
               (size_t)(lane >> 1) * 128 + r * 2 + (lane & 1), v);
      wave_vmcnt0();
      if (lane == 0) coh_st32(slotg + r * 4, (unsigned)(t + 2));
    }
    // (I) shadow: x output + x@Wih for t+1
    dout[OUT_X + (size_t)(pos * 32 + pb) * 1024 + dir * 512 + gj] = m ? h2 : 0.f;
    if (!last) {
      int tn = t + 1;
      int posA = (dir == 0) ? tn : ((tn < lenrow) ? (lenrow - 1 - tn) : tn);
      size_t rowb = (size_t)(posA * 32 + arow) * 512;
      f32x4 ax = {0.f, 0.f, 0.f, 0.f};
#pragma unroll 4
      for (int kb = 0; kb < 32; ++kb) {
        const u16* Asrc = (kb < 16) ? (out0F + rowb + kb * 32 + kq * 8)
                                    : (out0B + rowb + (kb - 16) * 32 + kq * 8);
        ax = mfma_bf(ld_bf8(Asrc), lds_ld16(sWih, colN, 2048, (kb * 32 + kq * 8) * 2), ax);
      }
      accx = ax;
      // (J) wait
      if (wid == 0) poll64(slotg, (unsigned)(t + 2));
      __syncthreads();
    }
  }

  // epilogue: finals + tail-zero x rows [Lmax*32, SB) for this dir half
  dout[OUT_FH + ((size_t)(2 + dir) * 32 + pb) * 512 + gj] = hreg;
  dout[OUT_FC + ((size_t)(2 + dir) * 32 + pb) * 512 + gj] = creg;
  for (int row = Lmax * 32 + r; row < SB_; row += 64) {
    ((u64*)(dout + OUT_X + (size_t)row * 1024 + dir * 512))[tid] = 0;
  }
}

// ---------------- penalty writeback ----------------
__global__ void k_final(const float* __restrict__ pen, float* __restrict__ dout) {
  if (threadIdx.x == 0 && blockIdx.x == 0) dout[OUT_PEN] = pen[0];
}

// ---------------- host ----------------
extern "C" void kernel_launch(void* const* d_in, const int* in_sizes, int n_in,
                              void* d_out, int out_size, void* d_ws, size_t ws_size,
                              hipStream_t stream) {
  (void)in_sizes; (void)n_in; (void)out_size; (void)ws_size;
  const int*   seq   = (const int*)d_in[0];
  const int*   lens  = (const int*)d_in[1];
  const float* emb1  = (const float*)d_in[2];
  const float* emb2  = (const float*)d_in[3];
  const float* emb3  = (const float*)d_in[4];
  const float* W_et  = (const float*)d_in[5];
  const float* b_et  = (const float*)d_in[6];
  const float* W_ct  = (const float*)d_in[7];
  const float* b_ct  = (const float*)d_in[8];
  const float* W_sc  = (const float*)d_in[9];
  const float* W_g   = (const float*)d_in[11];
  const float* b_g   = (const float*)d_in[12];
  const float* h0f   = (const float*)d_in[13];
  const float* c0f   = (const float*)d_in[14];
  const float* h0b   = (const float*)d_in[15];
  const float* c0b   = (const float*)d_in[16];
  const float* Wih   = (const float*)d_in[17];
  const float* Whh   = (const float*)d_in[18];
  const float* bih   = (const float*)d_in[19];
  const float* bhh   = (const float*)d_in[20];
  float* out = (float*)d_out;
  char* ws = (char*)d_ws;

  unsigned* slots = (unsigned*)(ws + WS_SLOTS);
  unsigned* stag  = (unsigned*)(ws + WS_STAG);
  float* pen    = (float*)(ws + WS_PEN);
  float* spart  = (float*)(ws + WS_SPART);
  u16* hgbuf = (u16*)(ws + WS_HG);
  u16* wEt  = (u16*)(ws + WS_WET);
  u16* wCt  = (u16*)(ws + WS_WCT);
  u16* wIh0 = (u16*)(ws + WS_WIH0);
  u16* wHh0 = (u16*)(ws + WS_WHH0);
  u16* wIh1 = (u16*)(ws + WS_WIH1);
  u16* wHh1 = (u16*)(ws + WS_WHH1);
  u16* wGg  = (u16*)(ws + WS_WG);
  u16* eK   = (u16*)(ws + WS_EK);
  float* eT = (float*)(ws + WS_ET);
  u16* pF   = (u16*)(ws + WS_PREDF);
  u16* pB   = (u16*)(ws + WS_PREDB);
  u16* o0F  = (u16*)(ws + WS_OUT0F);
  u16* o0B  = (u16*)(ws + WS_OUT0B);

  hipMemsetAsync(ws, 0, 6400, stream);   // slots + stag + pen

  // weight conversions to bf16
  hipLaunchKernelGGL(k_f2bf, dim3(512), dim3(256), 0, stream, W_et, wEt, 524288);
  hipLaunchKernelGGL(k_f2bf, dim3(512), dim3(256), 0, stream, W_ct, wCt, 262144);
  hipLaunchKernelGGL(k_f2bf, dim3(2048), dim3(256), 0, stream, Wih, wIh0, 4194304);
  hipLaunchKernelGGL(k_f2bf, dim3(2048), dim3(256), 0, stream, Wih + 4194304, wIh1, 4194304);
  hipLaunchKernelGGL(k_f2bf, dim3(1024), dim3(256), 0, stream, Whh, wHh0, 2097152);
  hipLaunchKernelGGL(k_f2bf, dim3(1024), dim3(256), 0, stream, Whh + 2097152, wHh1, 2097152);
  hipLaunchKernelGGL(k_f2bf, dim3(1024), dim3(256), 0, stream, W_g, wGg, 2097152);

  hipLaunchKernelGGL(k_gather, dim3(SB_), dim3(256), 0, stream,
                     seq, lens, emb1, emb2, emb3, eK, pen);
  hipLaunchKernelGGL(k_gemm_et, dim3(1536), dim3(256), 0, stream, eK, wEt, b_et, eT);
  hipLaunchKernelGGL(k_scan0, dim3(128), dim3(256), 0, stream,
                     eK, eT, wIh0, wHh0, wCt, W_sc, b_ct, bih, bhh, lens,
                     h0f, c0f, h0b, c0b, hgbuf, spart, o0F, o0B, pF, pB, out, slots, stag);
  hipLaunchKernelGGL(k_scan1, dim3(128), dim3(256), 0, stream,
                     o0F, o0B, wIh1, wHh1, bih, bhh, lens,
                     h0f, c0f, h0b, c0b, hgbuf, out, slots);
  hipLaunchKernelGGL(k_gemm_gate, dim3(1024), dim3(256), 0, stream,
                     pF, pB, wGg, b_g, out + OUT_PE);
  hipLaunchKernelGGL(k_final, dim3(1), dim3(64), 0, stream, pen, out);
}

// Round 8
// 14324.977 us; speedup vs baseline: 1.1651x; 1.1651x over previous
//
#include <hip/hip_runtime.h>

typedef unsigned short u16;
typedef unsigned long long u64;
typedef __bf16 bf16_t;
typedef bf16_t bf16x8 __attribute__((ext_vector_type(8)));
typedef float f32x4 __attribute__((ext_vector_type(4)));

#define DEVFN static __device__ __forceinline__

constexpr int S_ = 512, B_ = 32, H_ = 512, E_ = 1024;
constexpr int SB_ = S_ * B_;                 // 16384

// ---------------- d_out offsets (floats) ----------------
constexpr size_t OUT_FH  = 0;                 // final_h (4,32,512)
constexpr size_t OUT_FC  = 65536;             // final_c (4,32,512)
constexpr size_t OUT_X   = 131072;            // x (512,32,1024)
constexpr size_t OUT_PEN = 16908288;          // penalty (scalar)
constexpr size_t OUT_PE  = 16908289;          // pred_emb (512,32,1024)

// ---------------- ws offsets (bytes) ----------------
constexpr size_t WS_SLOTS = 0;                          // [4][64][4] u32 = 4096
constexpr size_t WS_STAG  = 4096;                       // [2][64][4] u32 = 2048
constexpr size_t WS_PEN   = 6144;                       // 256
constexpr size_t WS_SPART = 6400;                       // [2][3][32][32] f32 = 24576
constexpr size_t WS_HG    = 30976;                      // [2][2][32][512] bf16 = 131072
constexpr size_t WS_WET   = 237824;                     // 512x1024 bf16
constexpr size_t WS_WCT   = 1286400;                    // 512x512 bf16
constexpr size_t WS_WIH0  = 1810688;                    // [2][2048][1024] bf16
constexpr size_t WS_WHH0  = 10199296;                   // [2][2048][512] bf16
constexpr size_t WS_WIH1  = 14393600;
constexpr size_t WS_WHH1  = 22782208;
constexpr size_t WS_WG    = 26976512;                   // [1024][2048] bf16
constexpr size_t WS_EK    = 31170816;                   // [3][SB][1024] bf16
constexpr size_t WS_ET    = 131834112;                  // [3][SB][512] f32
constexpr size_t WS_PREDF = 232497408;                  // [SB][1024] bf16
constexpr size_t WS_PREDB = 266051840;
constexpr size_t WS_OUT0F = 299606272;                  // [SB][512] bf16
constexpr size_t WS_OUT0B = 316383488;                  // end ~318MB

// ---------------- helpers ----------------
DEVFN u16 f2bf(float f) {
  union { float f; unsigned u; } v; v.f = f;
  unsigned u = v.u;
  unsigned r = (u + 0x7fffu + ((u >> 16) & 1u)) >> 16;
  return (u16)r;
}
DEVFN float bf2f(u16 h) {
  union { unsigned u; float f; } v; v.u = ((unsigned)h) << 16;
  return v.f;
}
DEVFN float sigm(float x) { return 1.f / (1.f + __expf(-x)); }
DEVFN float tanh_f(float x) { float e = __expf(2.f * x); return 1.f - 2.f / (e + 1.f); }
DEVFN bf16x8 ld_bf8(const u16* p) { return *reinterpret_cast<const bf16x8*>(p); }
DEVFN f32x4 mfma_bf(bf16x8 a, bf16x8 b, f32x4 c) {
  return __builtin_amdgcn_mfma_f32_16x16x32_bf16(a, b, c, 0, 0, 0);
}
// XOR-swizzled LDS tile access
DEVFN void lds_st16(u16* base, int row, int rowBytes, int byteCol, bf16x8 v) {
  *reinterpret_cast<bf16x8*>((char*)base + row * rowBytes + (byteCol ^ ((row & 7) << 4))) = v;
}
DEVFN void lds_st8(u16* base, int row, int rowBytes, int byteCol, u64 v) {
  *reinterpret_cast<u64*>((char*)base + row * rowBytes + (byteCol ^ ((row & 7) << 4))) = v;
}
DEVFN bf16x8 lds_ld16(const u16* base, int row, int rowBytes, int byteCol) {
  return *reinterpret_cast<const bf16x8*>((const char*)base + row * rowBytes + (byteCol ^ ((row & 7) << 4)));
}

// Coherent-point (sc1) accessors — proven rounds 5-7.
DEVFN u64 coh_ld64(const u64* p) {
  return __hip_atomic_load(p, __ATOMIC_RELAXED, __HIP_MEMORY_SCOPE_AGENT);
}
DEVFN void coh_st64(u64* p, u64 v) {
  __hip_atomic_store(p, v, __ATOMIC_RELAXED, __HIP_MEMORY_SCOPE_AGENT);
}
DEVFN unsigned coh_ld32(const unsigned* p) {
  return __hip_atomic_load(p, __ATOMIC_RELAXED, __HIP_MEMORY_SCOPE_AGENT);
}
DEVFN void coh_st32(unsigned* p, unsigned v) {
  __hip_atomic_store(p, v, __ATOMIC_RELAXED, __HIP_MEMORY_SCOPE_AGENT);
}
DEVFN void wave_vmcnt0() { asm volatile("s_waitcnt vmcnt(0)" ::: "memory"); }

// 64-slot poll (wave-level): lane i polls slot i.
DEVFN void poll64(const unsigned* tags, unsigned target) {
  int lane = threadIdx.x & 63;
  for (;;) {
    unsigned v = coh_ld32(tags + lane * 4);
    if (__all(v >= target)) break;
    __builtin_amdgcn_s_sleep(1);
  }
  asm volatile("" ::: "memory");
}

// ---------------- fp32 -> bf16 convert ----------------
__global__ void k_f2bf(const float* __restrict__ src, u16* __restrict__ dst, int n) {
  for (int i = blockIdx.x * blockDim.x + threadIdx.x; i < n; i += gridDim.x * blockDim.x)
    dst[i] = f2bf(src[i]);
}

// ---------------- gather embeddings + penalty ----------------
__global__ __launch_bounds__(256) void k_gather(
    const int* __restrict__ seq, const int* __restrict__ lengths,
    const float* __restrict__ emb1, const float* __restrict__ emb2, const float* __restrict__ emb3,
    u16* __restrict__ eK, float* __restrict__ pen) {
  int s = blockIdx.x;              // = t*32 + b
  int t = s >> 5, b = s & 31;
  int tid = threadIdx.x;
  int tok = seq[s];
  const float4* p1 = (const float4*)(emb1 + (size_t)tok * 1024);
  const float4* p2 = (const float4*)(emb2 + (size_t)tok * 1024);
  const float4* p3 = (const float4*)(emb3 + (size_t)tok * 1024);
  float4 a = p1[tid], c = p2[tid], d = p3[tid];
  size_t rb = (size_t)s * 1024 + tid * 4;
  uint2 pk;
  pk.x = f2bf(a.x) | ((unsigned)f2bf(a.y) << 16); pk.y = f2bf(a.z) | ((unsigned)f2bf(a.w) << 16);
  *(uint2*)(eK + rb) = pk;
  pk.x = f2bf(c.x) | ((unsigned)f2bf(c.y) << 16); pk.y = f2bf(c.z) | ((unsigned)f2bf(c.w) << 16);
  *(uint2*)(eK + (size_t)SB_ * 1024 + rb) = pk;
  pk.x = f2bf(d.x) | ((unsigned)f2bf(d.y) << 16); pk.y = f2bf(d.z) | ((unsigned)f2bf(d.w) << 16);
  *(uint2*)(eK + (size_t)2 * SB_ * 1024 + rb) = pk;
  float v[6];
  v[0] = a.x*c.x + a.y*c.y + a.z*c.z + a.w*c.w;
  v[1] = a.x*d.x + a.y*d.y + a.z*d.z + a.w*d.w;
  v[2] = c.x*d.x + c.y*d.y + c.z*d.z + c.w*d.w;
  v[3] = a.x*a.x + a.y*a.y + a.z*a.z + a.w*a.w;
  v[4] = c.x*c.x + c.y*c.y + c.z*c.z + c.w*c.w;
  v[5] = d.x*d.x + d.y*d.y + d.z*d.z + d.w*d.w;
  for (int i = 0; i < 6; ++i)
    for (int m = 1; m < 64; m <<= 1) v[i] += __shfl_xor(v[i], m);
  __shared__ float red[4][6];
  int wid = tid >> 6, lane = tid & 63;
  if (lane == 0) for (int i = 0; i < 6; ++i) red[wid][i] = v[i];
  __syncthreads();
  if (tid == 0) {
    float r[6];
    for (int i = 0; i < 6; ++i) r[i] = red[0][i] + red[1][i] + red[2][i] + red[3][i];
    float c12 = r[0] / fmaxf(sqrtf(r[3]) * sqrtf(r[4]), 1e-8f);
    float c13 = r[1] / fmaxf(sqrtf(r[3]) * sqrtf(r[5]), 1e-8f);
    float c23 = r[2] / fmaxf(sqrtf(r[4]) * sqrtf(r[5]), 1e-8f);
    float p = fmaxf(c12 - 0.3f, 0.f) + fmaxf(c13 - 0.3f, 0.f) + fmaxf(c23 - 0.3f, 0.f);
    if (t < lengths[b] && p > 0.f) atomicAdd(pen, 2.f * p);   // fwd + bwd identical sums
  }
}

// ---------------- GEMM: ET = EK @ W_et^T + b_et ----------------
__global__ __launch_bounds__(256) void k_gemm_et(
    const u16* __restrict__ A, const u16* __restrict__ Bw,
    const float* __restrict__ bias, float* __restrict__ C) {
  int bm = blockIdx.x % 384, bn = blockIdx.x / 384;
  int m0 = bm * 128, n0 = bn * 128;
  __shared__ u16 sA[128 * 64], sB[128 * 64];
  int tid = threadIdx.x, wid = tid >> 6, lane = tid & 63;
  int wm = wid & 1, wn = wid >> 1;
  f32x4 acc[4][4] = {};
  for (int kb = 0; kb < 16; ++kb) {
    __syncthreads();
    for (int c = tid; c < 1024; c += 256) {
      int row = c >> 3, q = c & 7;
      lds_st16(sA, row, 128, q * 16, ld_bf8(A + (size_t)(m0 + row) * 1024 + kb * 64 + q * 8));
      lds_st16(sB, row, 128, q * 16, ld_bf8(Bw + (size_t)(n0 + row) * 1024 + kb * 64 + q * 8));
    }
    __syncthreads();
    for (int kk = 0; kk < 2; ++kk) {
      bf16x8 af[4], bf[4];
      int bc = kk * 64 + (lane >> 4) * 16;
      for (int i = 0; i < 4; ++i) {
        af[i] = lds_ld16(sA, wm * 64 + i * 16 + (lane & 15), 128, bc);
        bf[i] = lds_ld16(sB, wn * 64 + i * 16 + (lane & 15), 128, bc);
      }
      for (int i = 0; i < 4; ++i)
        for (int j = 0; j < 4; ++j) acc[i][j] = mfma_bf(af[i], bf[j], acc[i][j]);
    }
  }
  for (int i = 0; i < 4; ++i)
    for (int j = 0; j < 4; ++j) {
      int m = m0 + wm * 64 + i * 16 + (lane >> 4) * 4;
      int n = n0 + wn * 64 + j * 16 + (lane & 15);
      float bn_ = bias[n & 511];
      for (int r = 0; r < 4; ++r) C[(size_t)(m + r) * 512 + n] = acc[i][j][r] + bn_;
    }
}

// ---------------- GEMM: gate + pred_emb epilogue ----------------
__global__ __launch_bounds__(256) void k_gemm_gate(
    const u16* __restrict__ pF, const u16* __restrict__ pB, const u16* __restrict__ Wg,
    const float* __restrict__ bias, float* __restrict__ outPE) {
  int bm = blockIdx.x % 128, bn = blockIdx.x / 128;
  int m0 = bm * 128, n0 = bn * 128;
  __shared__ u16 sA[128 * 64], sB[128 * 64];
  int tid = threadIdx.x, wid = tid >> 6, lane = tid & 63;
  int wm = wid & 1, wn = wid >> 1;
  f32x4 acc[4][4] = {};
  for (int kb = 0; kb < 32; ++kb) {
    __syncthreads();
    const u16* Asrc = (kb < 16) ? pF : pB;
    int kof = (kb < 16) ? kb * 64 : (kb - 16) * 64;
    for (int c = tid; c < 1024; c += 256) {
      int row = c >> 3, q = c & 7;
      lds_st16(sA, row, 128, q * 16, ld_bf8(Asrc + (size_t)(m0 + row) * 1024 + kof + q * 8));
      lds_st16(sB, row, 128, q * 16, ld_bf8(Wg + (size_t)(n0 + row) * 2048 + kb * 64 + q * 8));
    }
    __syncthreads();
    for (int kk = 0; kk < 2; ++kk) {
      bf16x8 af[4], bf[4];
      int bc = kk * 64 + (lane >> 4) * 16;
      for (int i = 0; i < 4; ++i) {
        af[i] = lds_ld16(sA, wm * 64 + i * 16 + (lane & 15), 128, bc);
        bf[i] = lds_ld16(sB, wn * 64 + i * 16 + (lane & 15), 128, bc);
      }
      for (int i = 0; i < 4; ++i)
        for (int j = 0; j < 4; ++j) acc[i][j] = mfma_bf(af[i], bf[j], acc[i][j]);
    }
  }
  for (int i = 0; i < 4; ++i)
    for (int j = 0; j < 4; ++j) {
      int m = m0 + wm * 64 + i * 16 + (lane >> 4) * 4;
      int n = n0 + wn * 64 + j * 16 + (lane & 15);
      float bn_ = bias[n];
      for (int r = 0; r < 4; ++r) {
        float g = sigm(acc[i][j][r] + bn_);
        size_t idx = (size_t)(m + r) * 1024 + n;
        float a = bf2f(pF[idx]), b = bf2f(pB[idx]);
        outPE[idx] = a * g + b * (1.f - g);
      }
    }
}

// ---------------- layer-0 bidirectional scan ----------------
__global__ __launch_bounds__(256, 1) void k_scan0(
    const u16* __restrict__ eK, const float* __restrict__ eT,
    const u16* __restrict__ wIh0, const u16* __restrict__ wHh0, const u16* __restrict__ wCt,
    const float* __restrict__ Wsc, const float* __restrict__ bct,
    const float* __restrict__ bih, const float* __restrict__ bhh,
    const int* __restrict__ lengths,
    const float* __restrict__ h0f, const float* __restrict__ c0f,
    const float* __restrict__ h0b, const float* __restrict__ c0b,
    u16* __restrict__ hg, float* __restrict__ spart,
    u16* __restrict__ out0F, u16* __restrict__ out0B,
    u16* __restrict__ predF, u16* __restrict__ predB,
    float* __restrict__ dout, unsigned* __restrict__ slots, unsigned* __restrict__ stag) {
  const int dir = blockIdx.x >> 6;
  const int r   = blockIdx.x & 63;
  const int tid = threadIdx.x, wid = tid >> 6, lane = tid & 63;

  const u16* Wih = wIh0 + (size_t)dir * 2048 * 1024;
  const u16* Whh = wHh0 + (size_t)dir * 2048 * 512;
  const float* bi = bih + dir * 2048;
  const float* bh = bhh + dir * 2048;
  u16* out0 = dir ? out0B : out0F;
  u16* predD = dir ? predB : predF;
  const float* h0 = dir ? h0b : h0f;
  const float* c0 = dir ? c0b : c0f;
  u16* myhg = hg + (size_t)dir * 2 * 32 * 512;          // [buf][32][512]
  float* spartD = spart + (size_t)dir * 3 * 32 * 32;
  unsigned* slotg = slots + dir * 64 * 4;
  unsigned* stagD = stag + dir * 64 * 4;

  __shared__ u16 sWih[32 * 1024];      // 32 n-rows x 1024 k (swizzled)
  __shared__ u16 sWhh[32 * 512];
  __shared__ u16 sH[32 * 512];         // staged h (coalesced exchange; R6-proven)
  __shared__ u16 sHpub[256];
  __shared__ float sPW[3][32][32];
  __shared__ float sHW[32][32];
  __shared__ float sSK[3][32];
  __shared__ float sWt[32][4];
  __shared__ float sBias[32];

  // ---- load weight slices into LDS (n = q*512 + r*8 + jl) ----
  for (int c = tid; c < 4096; c += 256) {
    int ln = c >> 7, q = c & 127;
    int n = (ln >> 3) * 512 + r * 8 + (ln & 7);
    lds_st16(sWih, ln, 2048, q * 16, ld_bf8(Wih + (size_t)n * 1024 + q * 8));
  }
  for (int c = tid; c < 2048; c += 256) {
    int ln = c >> 6, q = c & 63;
    int n = (ln >> 3) * 512 + r * 8 + (ln & 7);
    lds_st16(sWhh, ln, 1024, q * 16, ld_bf8(Whh + (size_t)n * 512 + q * 8));
  }
  if (tid < 32) {
    int n = (tid >> 3) * 512 + r * 8 + (tid & 7);
    sBias[tid] = bi[n] + bh[n];
  }

  const int pb = tid >> 3, pj = tid & 7;     // phase-2 ownership (b, j-local)
  const int gj = r * 8 + pj;
  float hreg = h0[gj], creg = c0[gj];
  const int lenb = lengths[pb];
  const int Lmax = lengths[0];               // sorted descending

  const int Mt = wid & 1, Nt = wid >> 1;
  const int arow = Mt * 16 + (lane & 15);    // b-row for A fragments
  const int lenrow = lengths[arow];
  const int kq = lane >> 4;
  const int colN = Nt * 16 + (lane & 15);
  const bool isctx = (r < 32) && (wid < 2);
  int lctx[4];
  if (isctx)
    for (int reg = 0; reg < 4; ++reg) lctx[reg] = lengths[Mt * 16 + kq * 4 + reg];

  // ---- initial h publish into buf0 + initial barrier ----
  sHpub[tid] = f2bf(hreg);
  __syncthreads();
  if (wid == 0) {
    u64 v = *reinterpret_cast<const u64*>(sHpub + lane * 4);
    coh_st64((u64*)myhg + (size_t)(lane >> 1) * 128 + r * 2 + (lane & 1), v);
    wave_vmcnt0();
    if (lane == 0) coh_st32(slotg + r * 4, 1u);
  }
  if (wid == 0) poll64(slotg, 1u);
  __syncthreads();

  // eT prefetch (step 0)
  float petU[3][4];
  if (isctx) {
    int j = r * 16 + (lane & 15);
    for (int reg = 0; reg < 4; ++reg) {
      int b = Mt * 16 + kq * 4 + reg;
      int lb = lctx[reg];
      int pos = (dir == 0) ? 0 : (lb - 1);
      size_t rowoff = (size_t)(pos * 32 + b) * 512 + j;
      for (int k = 0; k < 3; ++k) petU[k][reg] = eT[(size_t)k * SB_ * 512 + rowoff];
    }
  }

  for (int t = 0; t < Lmax; ++t) {
    const bool last = (t == Lmax - 1);
    int posA = (dir == 0) ? t : ((t < lenrow) ? (lenrow - 1 - t) : t);
    size_t ebase = (size_t)(posA * 32 + arow) * 1024;
    // ===== stage h (issue coherent loads; latency hidden under PW k=0) =====
    u64 hv[16];
    {
      const u64* src = (const u64*)(myhg + (size_t)(t & 1) * 32 * 512);
#pragma unroll
      for (int i = 0; i < 16; ++i) hv[i] = coh_ld64(src + tid + i * 256);
    }
    // PW k=0 (independent of h)
    {
      const u16* Ek = eK + ebase;
      f32x4 acc = {0.f, 0.f, 0.f, 0.f};
#pragma unroll 4
      for (int kb = 0; kb < 32; ++kb)
        acc = mfma_bf(ld_bf8(Ek + kb * 32 + kq * 8),
                      lds_ld16(sWih, colN, 2048, (kb * 32 + kq * 8) * 2), acc);
      int rb = Mt * 16 + kq * 4;
      for (int reg = 0; reg < 4; ++reg) sPW[0][rb + reg][colN] = acc[reg];
    }
#pragma unroll
    for (int i = 0; i < 16; ++i) {
      int c = tid + i * 256, row = c >> 7, q = c & 127;
      lds_st8(sH, row, 1024, q * 8, hv[i]);
    }
    __syncthreads();   // sH ready
    // ===== hWhh (all waves) =====
    {
      f32x4 acc = {0.f, 0.f, 0.f, 0.f};
#pragma unroll
      for (int kb = 0; kb < 16; ++kb)
        acc = mfma_bf(lds_ld16(sH, arow, 1024, (kb * 32 + kq * 8) * 2),
                      lds_ld16(sWhh, colN, 1024, (kb * 32 + kq * 8) * 2), acc);
      int rb = Mt * 16 + kq * 4;
      for (int reg = 0; reg < 4; ++reg) sHW[rb + reg][colN] = acc[reg];
    }
    // ===== ctx + score partials + per-wave tag (producer waves) =====
    if (isctx) {
      f32x4 acc = {0.f, 0.f, 0.f, 0.f};
      int j = r * 16 + (lane & 15);
      const u16* Wctp = wCt + (size_t)j * 512;
#pragma unroll
      for (int kb = 0; kb < 16; ++kb)
        acc = mfma_bf(lds_ld16(sH, arow, 1024, (kb * 32 + kq * 8) * 2),
                      ld_bf8(Wctp + kb * 32 + kq * 8), acc);
      float wsc = Wsc[j], bctj = bct[j];
      for (int k = 0; k < 3; ++k)
        for (int reg = 0; reg < 4; ++reg) {
          float v = tanh_f(petU[k][reg] + acc[reg] + bctj) * wsc;
          v += __shfl_xor(v, 1); v += __shfl_xor(v, 2);
          v += __shfl_xor(v, 4); v += __shfl_xor(v, 8);
          if ((lane & 15) == 0) {
            int b = Mt * 16 + kq * 4 + reg;
            union { float f; unsigned u; } w; w.f = v;
            coh_st32((unsigned*)(spartD + (k * 32 + b) * 32 + r), w.u);
          }
        }
      wave_vmcnt0();
      if (lane == 0) coh_st32(stagD + (r * 2 + Mt) * 4, (unsigned)(t + 1));
    }
    // eT prefetch for t+1 (issued after tag; drains under PW k=1,2 + poll)
    float petN[3][4];
    if (isctx && t + 1 < Lmax) {
      int j = r * 16 + (lane & 15);
      for (int reg = 0; reg < 4; ++reg) {
        int b = Mt * 16 + kq * 4 + reg;
        int lb = lctx[reg];
        int tn = t + 1;
        int pos = (dir == 0) ? tn : ((tn < lb) ? (lb - 1 - tn) : tn);
        size_t rowoff = (size_t)(pos * 32 + b) * 512 + j;
        for (int k = 0; k < 3; ++k) petN[k][reg] = eT[(size_t)k * SB_ * 512 + rowoff];
      }
    }
    // ===== PW k=1,2 (A-poll shadow) =====
    for (int k = 1; k < 3; ++k) {
      const u16* Ek = eK + (size_t)k * SB_ * 1024 + ebase;
      f32x4 acc = {0.f, 0.f, 0.f, 0.f};
#pragma unroll 4
      for (int kb = 0; kb < 32; ++kb)
        acc = mfma_bf(ld_bf8(Ek + kb * 32 + kq * 8),
                      lds_ld16(sWih, colN, 2048, (kb * 32 + kq * 8) * 2), acc);
      int rb = Mt * 16 + kq * 4;
      for (int reg = 0; reg < 4; ++reg) sPW[k][rb + reg][colN] = acc[reg];
    }
    // ===== consume score partials (waves 0-1 poll producer tags) =====
    if (wid < 2) poll64(stagD, (unsigned)(t + 1));
    if (tid < 96) {
      int k = tid >> 5, b = tid & 31;
      const u64* sp = (const u64*)(spartD + (k * 32 + b) * 32);
      float s = 0.f;
#pragma unroll
      for (int i = 0; i < 16; ++i) {
        union { u64 u; float f[2]; } w; w.u = coh_ld64(sp + i);
        s += w.f[0] + w.f[1];
      }
      sSK[k][b] = s;
    }
    __syncthreads();
    if (tid < 32) {
      float s0 = sSK[0][tid], s1 = sSK[1][tid], s2 = sSK[2][tid];
      float mx = fmaxf(s0, fmaxf(s1, s2));
      float e0 = __expf(s0 - mx), e1 = __expf(s1 - mx), e2 = __expf(s2 - mx);
      float inv = 1.f / (e0 + e1 + e2);
      sWt[tid][0] = e0 * inv; sWt[tid][1] = e1 * inv; sWt[tid][2] = e2 * inv;
    }
    __syncthreads();
    // ===== gate + cell update =====
    float w0 = sWt[pb][0], w1 = sWt[pb][1], w2 = sWt[pb][2];
    float h2, c2; bool m; int pos;
    {
      float gq[4];
      for (int q = 0; q < 4; ++q) {
        int cl = q * 8 + pj;
        gq[q] = w0 * sPW[0][pb][cl] + w1 * sPW[1][pb][cl] + w2 * sPW[2][pb][cl]
              + sHW[pb][cl] + sBias[cl];
      }
      float ig = sigm(gq[0]), fg = sigm(gq[1]), gg = tanh_f(gq[2]), og = sigm(gq[3]);
      c2 = fg * creg + ig * gg;
      h2 = og * tanh_f(c2);
      m = (t < lenb);
      if (m) { creg = c2; hreg = h2; }
      pos = (dir == 0) ? t : ((t < lenb) ? (lenb - 1 - t) : t);
      sHpub[tid] = f2bf(hreg);
    }
    __syncthreads();   // sHpub ready for wave 0
    // ===== h publish + arrive (wave 0 only) =====
    if (!last && wid == 0) {
      u64 v = *reinterpret_cast<const u64*>(sHpub + lane * 4);
      coh_st64((u64*)(myhg + (size_t)((t + 1) & 1) * 32 * 512) +
               (size_t)(lane >> 1) * 128 + r * 2 + (lane & 1), v);
      wave_vmcnt0();
      if (lane == 0) coh_st32(slotg + r * 4, (unsigned)(t + 2));
    }
    // ===== B-shadow: out0 + preds (plain stores) =====
    {
      out0[(size_t)(pos * 32 + pb) * 512 + gj] = f2bf(m ? h2 : 0.f);
      size_t rowb = (size_t)(pos * 32 + pb) * 1024;
      int e0i = r * 16 + (tid & 7) * 2;
      for (int ii = 0; ii < 2; ++ii) {
        int e = e0i + ii;
        float xv = w0 * bf2f(eK[rowb + e])
                 + w1 * bf2f(eK[(size_t)SB_ * 1024 + rowb + e])
                 + w2 * bf2f(eK[(size_t)2 * SB_ * 1024 + rowb + e]);
        predD[rowb + e] = f2bf(m ? xv : 0.f);
      }
    }
    // rotate eT prefetch
    if (isctx)
      for (int k = 0; k < 3; ++k)
        for (int reg = 0; reg < 4; ++reg) petU[k][reg] = petN[k][reg];
    // ===== wait for all h publishes =====
    if (!last) {
      if (wid == 0) poll64(slotg, (unsigned)(t + 2));
      __syncthreads();
    }
  }

  // epilogue: finals + tail-zero rows [Lmax*32, SB)
  dout[OUT_FH + ((size_t)dir * 32 + pb) * 512 + gj] = hreg;
  dout[OUT_FC + ((size_t)dir * 32 + pb) * 512 + gj] = creg;
  for (int row = Lmax * 32 + r; row < SB_; row += 64) {
    if (tid < 128) ((u64*)(out0 + (size_t)row * 512))[tid] = 0;
    ((u64*)(predD + (size_t)row * 1024))[tid] = 0;
  }
}

// ---------------- layer-1 bidirectional scan ----------------
__global__ __launch_bounds__(256, 1) void k_scan1(
    const u16* __restrict__ out0F, const u16* __restrict__ out0B,
    const u16* __restrict__ wIh1, const u16* __restrict__ wHh1,
    const float* __restrict__ bih, const float* __restrict__ bhh,
    const int* __restrict__ lengths,
    const float* __restrict__ h0f, const float* __restrict__ c0f,
    const float* __restrict__ h0b, const float* __restrict__ c0b,
    u16* __restrict__ hg, float* __restrict__ dout, unsigned* __restrict__ slots) {
  const int dir = blockIdx.x >> 6;
  const int r   = blockIdx.x & 63;
  const int tid = threadIdx.x, wid = tid >> 6, lane = tid & 63;

  const u16* Wih = wIh1 + (size_t)dir * 2048 * 1024;
  const u16* Whh = wHh1 + (size_t)dir * 2048 * 512;
  const float* bi = bih + (2 + dir) * 2048;
  const float* bh = bhh + (2 + dir) * 2048;
  const float* h0 = dir ? h0b : h0f;
  const float* c0 = dir ? c0b : c0f;
  unsigned* slotg = slots + (2 + dir) * 64 * 4;

  __shared__ u16 sWih[32 * 1024];
  __shared__ u16 sWhh[32 * 512];
  __shared__ u16 sH[32 * 512];
  __shared__ u16 sHpub[256];
  __shared__ float sG[32][32];
  __shared__ float sBias[32];

  for (int c = tid; c < 4096; c += 256) {
    int ln = c >> 7, q = c & 127;
    int n = (ln >> 3) * 512 + r * 8 + (ln & 7);
    lds_st16(sWih, ln, 2048, q * 16, ld_bf8(Wih + (size_t)n * 1024 + q * 8));
  }
  for (int c = tid; c < 2048; c += 256) {
    int ln = c >> 6, q = c & 63;
    int n = (ln >> 3) * 512 + r * 8 + (ln & 7);
    lds_st16(sWhh, ln, 1024, q * 16, ld_bf8(Whh + (size_t)n * 512 + q * 8));
  }
  if (tid < 32) {
    int n = (tid >> 3) * 512 + r * 8 + (tid & 7);
    sBias[tid] = bi[n] + bh[n];
  }

  const int pb = tid >> 3, pj = tid & 7;
  const int gj = r * 8 + pj;
  float hreg = h0[gj], creg = c0[gj];
  const int lenb = lengths[pb];
  const int Lmax = lengths[0];
  const int Mt = wid & 1, Nt = wid >> 1;
  const int arow = Mt * 16 + (lane & 15);
  const int lenrow = lengths[arow];
  const int kq = lane >> 4;
  const int colN = Nt * 16 + (lane & 15);

  __syncthreads();   // sWih staged
  // x@Wih for t=0
  f32x4 accx = {0.f, 0.f, 0.f, 0.f};
  {
    int posA = (dir == 0) ? 0 : (lenrow - 1);
    size_t rowb = (size_t)(posA * 32 + arow) * 512;
#pragma unroll 4
    for (int kb = 0; kb < 32; ++kb) {
      const u16* Asrc = (kb < 16) ? (out0F + rowb + kb * 32 + kq * 8)
                                  : (out0B + rowb + (kb - 16) * 32 + kq * 8);
      accx = mfma_bf(ld_bf8(Asrc), lds_ld16(sWih, colN, 2048, (kb * 32 + kq * 8) * 2), accx);
    }
  }

  // initial h publish into buf0 ([buf][dir][32][512]) + initial barrier
  sHpub[tid] = f2bf(hreg);
  __syncthreads();
  if (wid == 0) {
    u64 v = *reinterpret_cast<const u64*>(sHpub + lane * 4);
    coh_st64((u64*)(hg + (size_t)(0 * 2 + dir) * 32 * 512) +
             (size_t)(lane >> 1) * 128 + r * 2 + (lane & 1), v);
    wave_vmcnt0();
    if (lane == 0) coh_st32(slotg + r * 4, 1u);
  }
  if (wid == 0) poll64(slotg, 1u);
  __syncthreads();

  for (int t = 0; t < Lmax; ++t) {
    const bool last = (t == Lmax - 1);
    // stage h_t into LDS (coalesced; R6-proven)
    {
      const u64* src = (const u64*)(hg + (size_t)((t & 1) * 2 + dir) * 32 * 512);
      u64 hv[16];
#pragma unroll
      for (int i = 0; i < 16; ++i) hv[i] = coh_ld64(src + tid + i * 256);
#pragma unroll
      for (int i = 0; i < 16; ++i) {
        int c = tid + i * 256, row = c >> 7, q = c & 127;
        lds_st8(sH, row, 1024, q * 8, hv[i]);
      }
    }
    __syncthreads();
    // h @ Whh^T on top of prefetched x@Wih
    f32x4 acc = accx;
#pragma unroll
    for (int kb = 0; kb < 16; ++kb)
      acc = mfma_bf(lds_ld16(sH, arow, 1024, (kb * 32 + kq * 8) * 2),
                    lds_ld16(sWhh, colN, 1024, (kb * 32 + kq * 8) * 2), acc);
    {
      int rb = Mt * 16 + kq * 4;
      for (int reg = 0; reg < 4; ++reg) sG[rb + reg][colN] = acc[reg];
    }
    __syncthreads();
    // gate
    float h2, c2; bool m; int pos;
    {
      float gq[4];
      for (int q = 0; q < 4; ++q) gq[q] = sG[pb][q * 8 + pj] + sBias[q * 8 + pj];
      float ig = sigm(gq[0]), fg = sigm(gq[1]), gg = tanh_f(gq[2]), og = sigm(gq[3]);
      c2 = fg * creg + ig * gg;
      h2 = og * tanh_f(c2);
      m = (t < lenb);
      if (m) { creg = c2; hreg = h2; }
      pos = (dir == 0) ? t : ((t < lenb) ? (lenb - 1 - t) : t);
      sHpub[tid] = f2bf(hreg);
    }
    __syncthreads();
    // h publish + arrive (wave 0)
    if (!last && wid == 0) {
      u64 v = *reinterpret_cast<const u64*>(sHpub + lane * 4);
      coh_st64((u64*)(hg + (size_t)(((t + 1) & 1) * 2 + dir) * 32 * 512) +
               (size_t)(lane >> 1) * 128 + r * 2 + (lane & 1), v);
      wave_vmcnt0();
      if (lane == 0) coh_st32(slotg + r * 4, (unsigned)(t + 2));
    }
    // shadow: x output + x@Wih for t+1
    dout[OUT_X + (size_t)(pos * 32 + pb) * 1024 + dir * 512 + gj] = m ? h2 : 0.f;
    if (!last) {
      int tn = t + 1;
      int posA = (dir == 0) ? tn : ((tn < lenrow) ? (lenrow - 1 - tn) : tn);
      size_t rowb = (size_t)(posA * 32 + arow) * 512;
      f32x4 ax = {0.f, 0.f, 0.f, 0.f};
#pragma unroll 4
      for (int kb = 0; kb < 32; ++kb) {
        const u16* Asrc = (kb < 16) ? (out0F + rowb + kb * 32 + kq * 8)
                                    : (out0B + rowb + (kb - 16) * 32 + kq * 8);
        ax = mfma_bf(ld_bf8(Asrc), lds_ld16(sWih, colN, 2048, (kb * 32 + kq * 8) * 2), ax);
      }
      accx = ax;
      if (wid == 0) poll64(slotg, (unsigned)(t + 2));
      __syncthreads();
    }
  }

  // epilogue: finals + tail-zero x rows [Lmax*32, SB) for this dir half
  dout[OUT_FH + ((size_t)(2 + dir) * 32 + pb) * 512 + gj] = hreg;
  dout[OUT_FC + ((size_t)(2 + dir) * 32 + pb) * 512 + gj] = creg;
  for (int row = Lmax * 32 + r; row < SB_; row += 64) {
    ((u64*)(dout + OUT_X + (size_t)row * 1024 + dir * 512))[tid] = 0;
  }
}

// ---------------- penalty writeback ----------------
__global__ void k_final(const float* __restrict__ pen, float* __restrict__ dout) {
  if (threadIdx.x == 0 && blockIdx.x == 0) dout[OUT_PEN] = pen[0];
}

// ---------------- host ----------------
extern "C" void kernel_launch(void* const* d_in, const int* in_sizes, int n_in,
                              void* d_out, int out_size, void* d_ws, size_t ws_size,
                              hipStream_t stream) {
  (void)in_sizes; (void)n_in; (void)out_size; (void)ws_size;
  const int*   seq   = (const int*)d_in[0];
  const int*   lens  = (const int*)d_in[1];
  const float* emb1  = (const float*)d_in[2];
  const float* emb2  = (const float*)d_in[3];
  const float* emb3  = (const float*)d_in[4];
  const float* W_et  = (const float*)d_in[5];
  const float* b_et  = (const float*)d_in[6];
  const float* W_ct  = (const float*)d_in[7];
  const float* b_ct  = (const float*)d_in[8];
  const float* W_sc  = (const float*)d_in[9];
  const float* W_g   = (const float*)d_in[11];
  const float* b_g   = (const float*)d_in[12];
  const float* h0f   = (const float*)d_in[13];
  const float* c0f   = (const float*)d_in[14];
  const float* h0b   = (const float*)d_in[15];
  const float* c0b   = (const float*)d_in[16];
  const float* Wih   = (const float*)d_in[17];
  const float* Whh   = (const float*)d_in[18];
  const float* bih   = (const float*)d_in[19];
  const float* bhh   = (const float*)d_in[20];
  float* out = (float*)d_out;
  char* ws = (char*)d_ws;

  unsigned* slots = (unsigned*)(ws + WS_SLOTS);
  unsigned* stag  = (unsigned*)(ws + WS_STAG);
  float* pen    = (float*)(ws + WS_PEN);
  float* spart  = (float*)(ws + WS_SPART);
  u16* hgbuf = (u16*)(ws + WS_HG);
  u16* wEt  = (u16*)(ws + WS_WET);
  u16* wCt  = (u16*)(ws + WS_WCT);
  u16* wIh0 = (u16*)(ws + WS_WIH0);
  u16* wHh0 = (u16*)(ws + WS_WHH0);
  u16* wIh1 = (u16*)(ws + WS_WIH1);
  u16* wHh1 = (u16*)(ws + WS_WHH1);
  u16* wGg  = (u16*)(ws + WS_WG);
  u16* eK   = (u16*)(ws + WS_EK);
  float* eT = (float*)(ws + WS_ET);
  u16* pF   = (u16*)(ws + WS_PREDF);
  u16* pB   = (u16*)(ws + WS_PREDB);
  u16* o0F  = (u16*)(ws + WS_OUT0F);
  u16* o0B  = (u16*)(ws + WS_OUT0B);

  hipMemsetAsync(ws, 0, 6400, stream);   // slots + stag + pen

  // weight conversions to bf16
  hipLaunchKernelGGL(k_f2bf, dim3(512), dim3(256), 0, stream, W_et, wEt, 524288);
  hipLaunchKernelGGL(k_f2bf, dim3(512), dim3(256), 0, stream, W_ct, wCt, 262144);
  hipLaunchKernelGGL(k_f2bf, dim3(2048), dim3(256), 0, stream, Wih, wIh0, 4194304);
  hipLaunchKernelGGL(k_f2bf, dim3(2048), dim3(256), 0, stream, Wih + 4194304, wIh1, 4194304);
  hipLaunchKernelGGL(k_f2bf, dim3(1024), dim3(256), 0, stream, Whh, wHh0, 2097152);
  hipLaunchKernelGGL(k_f2bf, dim3(1024), dim3(256), 0, stream, Whh + 2097152, wHh1, 2097152);
  hipLaunchKernelGGL(k_f2bf, dim3(1024), dim3(256), 0, stream, W_g, wGg, 2097152);

  hipLaunchKernelGGL(k_gather, dim3(SB_), dim3(256), 0, stream,
                     seq, lens, emb1, emb2, emb3, eK, pen);
  hipLaunchKernelGGL(k_gemm_et, dim3(1536), dim3(256), 0, stream, eK, wEt, b_et, eT);
  hipLaunchKernelGGL(k_scan0, dim3(128), dim3(256), 0, stream,
                     eK, eT, wIh0, wHh0, wCt, W_sc, b_ct, bih, bhh, lens,
                     h0f, c0f, h0b, c0b, hgbuf, spart, o0F, o0B, pF, pB, out, slots, stag);
  hipLaunchKernelGGL(k_scan1, dim3(128), dim3(256), 0, stream,
                     o0F, o0B, wIh1, wHh1, bih, bhh, lens,
                     h0f, c0f, h0b, c0b, hgbuf, out, slots);
  hipLaunchKernelGGL(k_gemm_gate, dim3(1024), dim3(256), 0, stream,
                     pF, pB, wGg, b_g, out + OUT_PE);
  hipLaunchKernelGGL(k_final, dim3(1), dim3(64), 0, stream, pen, out);
}